// Round 1
// baseline (1153.269 us; speedup 1.0000x reference)
//
#include <hip/hip_runtime.h>

#define NN 12000
#define HH 32
#define TT 50
#define SPLITS 8
#define BM 128
#define KPER (NN / SPLITS) /* 1500, divisible by 4 */

typedef float f32x4 __attribute__((ext_vector_type(4)));

// ---------------- kernel 1: support = [z | a_t] @ W ----------------
__global__ void support_kernel(const float* __restrict__ tt,
                               const float* __restrict__ z,
                               const float* __restrict__ treat,
                               const float* __restrict__ W,
                               float* __restrict__ support) {
  int tid = blockIdx.x * blockDim.x + threadIdx.x;
  if (tid >= NN * HH) return;
  int row = tid >> 5;
  int col = tid & 31;
  int aidx = (int)(tt[0] * (float)(TT - 1));
  aidx = aidx < 0 ? 0 : (aidx > TT - 1 ? TT - 1 : aidx);
  float at = treat[row * TT + aidx];
  float acc = at * W[HH * HH + col];  // W row 32 (the a_t row)
  const float* zr = z + row * HH;
#pragma unroll
  for (int k = 0; k < HH; ++k) acc = fmaf(zr[k], W[k * HH + col], acc);
  support[tid] = acc;
}

// ---------------- kernel 2: partial[s] = adj[:, ks] @ support[ks, :] -------
// 256 threads: cg = tid&7 -> cols 4*cg..4*cg+3 ; rg = tid>>3 -> rows rg+32j
__global__ __launch_bounds__(256, 2) void spmm_kernel(
    const float* __restrict__ adj,
    const float* __restrict__ support,
    float* __restrict__ partial) {
  const int rb = blockIdx.x;
  const int s = blockIdx.y;
  const int tid = threadIdx.x;
  const int cg = tid & 7;
  const int rg = tid >> 3;
  const int k0 = s * KPER;

  int row[4];
  const f32x4* arow[4];
#pragma unroll
  for (int j = 0; j < 4; ++j) {
    int r = rb * BM + rg + 32 * j;
    row[j] = r;
    int rc = r < NN ? r : NN - 1;  // clamp; store is guarded
    arow[j] = (const f32x4*)(adj + (size_t)rc * NN + k0);
  }
  // B base: float4 index (k)*8 + cg
  const f32x4* bbase = ((const f32x4*)support) + (size_t)k0 * (HH / 4) + cg;

  f32x4 acc0 = (f32x4)0.f, acc1 = (f32x4)0.f, acc2 = (f32x4)0.f,
        acc3 = (f32x4)0.f;

  for (int k4 = 0; k4 < KPER / 4; ++k4) {
    f32x4 b0 = bbase[(size_t)(4 * k4 + 0) * 8];
    f32x4 b1 = bbase[(size_t)(4 * k4 + 1) * 8];
    f32x4 b2 = bbase[(size_t)(4 * k4 + 2) * 8];
    f32x4 b3 = bbase[(size_t)(4 * k4 + 3) * 8];
    f32x4 a0 = __builtin_nontemporal_load(arow[0] + k4);
    f32x4 a1 = __builtin_nontemporal_load(arow[1] + k4);
    f32x4 a2 = __builtin_nontemporal_load(arow[2] + k4);
    f32x4 a3 = __builtin_nontemporal_load(arow[3] + k4);
#define ROW_FMA(ACC, A)                      \
    ACC += A.x * b0; ACC += A.y * b1;        \
    ACC += A.z * b2; ACC += A.w * b3;
    ROW_FMA(acc0, a0)
    ROW_FMA(acc1, a1)
    ROW_FMA(acc2, a2)
    ROW_FMA(acc3, a3)
#undef ROW_FMA
  }

  f32x4* pout = (f32x4*)partial;
#pragma unroll
  for (int j = 0; j < 4; ++j) {
    if (row[j] < NN) {
      f32x4 v = j == 0 ? acc0 : (j == 1 ? acc1 : (j == 2 ? acc2 : acc3));
      pout[((size_t)s * NN + row[j]) * (HH / 4) + cg] = v;
    }
  }
}

// ---------------- kernel 3: out = relu(sum_s partial + b) ----------------
__global__ void combine_kernel(const float* __restrict__ partial,
                               const float* __restrict__ bias,
                               float* __restrict__ out) {
  int tid = blockIdx.x * blockDim.x + threadIdx.x;
  if (tid >= NN * HH / 4) return;
  int c0 = (tid & 7) * 4;
  f32x4 acc = *(const f32x4*)(bias + c0);
#pragma unroll
  for (int s = 0; s < SPLITS; ++s)
    acc += ((const f32x4*)partial)[(size_t)s * (NN * HH / 4) + tid];
  acc.x = fmaxf(acc.x, 0.f);
  acc.y = fmaxf(acc.y, 0.f);
  acc.z = fmaxf(acc.z, 0.f);
  acc.w = fmaxf(acc.w, 0.f);
  ((f32x4*)out)[tid] = acc;
}

extern "C" void kernel_launch(void* const* d_in, const int* in_sizes, int n_in,
                              void* d_out, int out_size, void* d_ws,
                              size_t ws_size, hipStream_t stream) {
  const float* t = (const float*)d_in[0];
  const float* z = (const float*)d_in[1];
  const float* adj = (const float*)d_in[2];
  const float* treat = (const float*)d_in[3];
  const float* W = (const float*)d_in[4];
  const float* b = (const float*)d_in[5];
  float* out = (float*)d_out;

  float* support = (float*)d_ws;               // 384000 floats
  float* partial = support + (size_t)NN * HH;  // 8 * 384000 floats

  support_kernel<<<(NN * HH + 255) / 256, 256, 0, stream>>>(t, z, treat, W,
                                                            support);
  dim3 grid((NN + BM - 1) / BM, SPLITS);
  spmm_kernel<<<grid, 256, 0, stream>>>(adj, support, partial);
  combine_kernel<<<(NN * HH / 4 + 255) / 256, 256, 0, stream>>>(partial, b,
                                                                out);
}

// Round 6
// 971.047 us; speedup vs baseline: 1.1877x; 1.1877x over previous
//
#include <hip/hip_runtime.h>

#define NN 12000
#define HH 32
#define TT 50
#define BM 96  /* 12000 / 96 = 125 row-blocks, exact */

typedef float f32x4 __attribute__((ext_vector_type(4)));

// ---------------- kernel 1: support = [z | a_t] @ W ----------------
__global__ void support_kernel(const float* __restrict__ tt,
                               const float* __restrict__ z,
                               const float* __restrict__ treat,
                               const float* __restrict__ W,
                               float* __restrict__ support) {
  int tid = blockIdx.x * blockDim.x + threadIdx.x;
  if (tid >= NN * HH) return;
  int row = tid >> 5;
  int col = tid & 31;
  int aidx = (int)(tt[0] * (float)(TT - 1));
  aidx = aidx < 0 ? 0 : (aidx > TT - 1 ? TT - 1 : aidx);
  float at = treat[row * TT + aidx];
  float acc = at * W[HH * HH + col];  // W row 32 (the a_t row)
  const float* zr = z + row * HH;
#pragma unroll
  for (int k = 0; k < HH; ++k) acc = fmaf(zr[k], W[k * HH + col], acc);
  support[tid] = acc;
}

// ---------------- kernel 2: partial[s] = adj[:, ks] @ support[ks, :] -------
// 256 threads: cg = tid&7 -> cols 4*cg..4*cg+3 ; rg = tid>>3 -> 3 rows rg+32j
__global__ __launch_bounds__(256, 8) void spmm_kernel(
    const float* __restrict__ adj,
    const float* __restrict__ support,
    float* __restrict__ partial,
    int kper) {
  const int rb = blockIdx.x;
  const int s = blockIdx.y;
  const int tid = threadIdx.x;
  const int cg = tid & 7;
  const int rg = tid >> 3;
  const int k0 = s * kper;

  const f32x4* arow0 = (const f32x4*)(adj + (size_t)(rb * BM + rg) * NN + k0);
  const f32x4* arow1 =
      (const f32x4*)(adj + (size_t)(rb * BM + rg + 32) * NN + k0);
  const f32x4* arow2 =
      (const f32x4*)(adj + (size_t)(rb * BM + rg + 64) * NN + k0);
  // B: float4 granules, row k has 8 granules; this thread reads granule cg.
  const f32x4* bptr = ((const f32x4*)support) + (size_t)k0 * (HH / 4) + cg;

  f32x4 acc0 = (f32x4)0.f, acc1 = (f32x4)0.f, acc2 = (f32x4)0.f;

  const int nk4 = kper >> 2;
  for (int k4 = 0; k4 < nk4; ++k4) {
    f32x4 b0 = bptr[0 * (HH / 4)];
    f32x4 b1 = bptr[1 * (HH / 4)];
    f32x4 b2 = bptr[2 * (HH / 4)];
    f32x4 b3 = bptr[3 * (HH / 4)];
    f32x4 a0 = arow0[k4];
    f32x4 a1 = arow1[k4];
    f32x4 a2 = arow2[k4];
#define ROW_FMA(ACC, A)               \
    ACC += A.x * b0; ACC += A.y * b1; \
    ACC += A.z * b2; ACC += A.w * b3;
    ROW_FMA(acc0, a0)
    ROW_FMA(acc1, a1)
    ROW_FMA(acc2, a2)
#undef ROW_FMA
    bptr += 4 * (HH / 4);
  }

  f32x4* pout = (f32x4*)partial;
  const size_t sbase = (size_t)s * NN;
  pout[(sbase + rb * BM + rg) * (HH / 4) + cg] = acc0;
  pout[(sbase + rb * BM + rg + 32) * (HH / 4) + cg] = acc1;
  pout[(sbase + rb * BM + rg + 64) * (HH / 4) + cg] = acc2;
}

// ---------------- kernel 3: out = relu(sum_s partial + b) ----------------
__global__ void combine_kernel(const float* __restrict__ partial,
                               const float* __restrict__ bias,
                               float* __restrict__ out, int splits) {
  int tid = blockIdx.x * blockDim.x + threadIdx.x;
  if (tid >= NN * HH / 4) return;
  int c0 = (tid & (HH / 4 - 1)) * 4;
  f32x4 acc = *(const f32x4*)(bias + c0);
  for (int s = 0; s < splits; ++s)
    acc += ((const f32x4*)partial)[(size_t)s * (NN * HH / 4) + tid];
  acc.x = fmaxf(acc.x, 0.f);
  acc.y = fmaxf(acc.y, 0.f);
  acc.z = fmaxf(acc.z, 0.f);
  acc.w = fmaxf(acc.w, 0.f);
  ((f32x4*)out)[tid] = acc;
}

extern "C" void kernel_launch(void* const* d_in, const int* in_sizes, int n_in,
                              void* d_out, int out_size, void* d_ws,
                              size_t ws_size, hipStream_t stream) {
  const float* t = (const float*)d_in[0];
  const float* z = (const float*)d_in[1];
  const float* adj = (const float*)d_in[2];
  const float* treat = (const float*)d_in[3];
  const float* W = (const float*)d_in[4];
  const float* b = (const float*)d_in[5];
  float* out = (float*)d_out;

  // pick largest split count whose partial buffer fits in d_ws
  const size_t elem = (size_t)NN * HH;  // floats per [N,H] buffer
  static const int split_opts[] = {15, 12, 10, 8, 6, 5, 4, 3, 2, 1};
  int splits = 1;
  for (int i = 0; i < 10; ++i) {
    if ((size_t)(split_opts[i] + 1) * elem * 4 <= ws_size) {
      splits = split_opts[i];
      break;
    }
  }
  const int kper = NN / splits;  // all options give kper % 4 == 0

  float* support = (float*)d_ws;          // NN*HH floats
  float* partial = support + elem;        // splits * NN*HH floats

  support_kernel<<<(NN * HH + 255) / 256, 256, 0, stream>>>(t, z, treat, W,
                                                            support);
  dim3 grid(NN / BM, splits);
  spmm_kernel<<<grid, 256, 0, stream>>>(adj, support, partial, kper);
  combine_kernel<<<(NN * HH / 4 + 255) / 256, 256, 0, stream>>>(partial, b, out,
                                                                splits);
}

// Round 7
// 854.723 us; speedup vs baseline: 1.3493x; 1.1361x over previous
//
#include <hip/hip_runtime.h>

#define NN 12000
#define HH 32
#define TT 50
#define BM 96            /* 12000 / 96 = 125 row-blocks, exact */
#define KC 160           /* k-rows per LDS chunk */
#define CHUNK_BYTES (KC * HH * 4) /* 20480 B = 5 x 4096 B stage issues */

typedef float f32x4 __attribute__((ext_vector_type(4)));

// ---------------- kernel 1: support = [z | a_t] @ W ----------------
__global__ void support_kernel(const float* __restrict__ tt,
                               const float* __restrict__ z,
                               const float* __restrict__ treat,
                               const float* __restrict__ W,
                               float* __restrict__ support) {
  int tid = blockIdx.x * blockDim.x + threadIdx.x;
  if (tid >= NN * HH) return;
  int row = tid >> 5;
  int col = tid & 31;
  int aidx = (int)(tt[0] * (float)(TT - 1));
  aidx = aidx < 0 ? 0 : (aidx > TT - 1 ? TT - 1 : aidx);
  float at = treat[row * TT + aidx];
  float acc = at * W[HH * HH + col];  // W row 32 (the a_t row)
  const float* zr = z + row * HH;
#pragma unroll
  for (int k = 0; k < HH; ++k) acc = fmaf(zr[k], W[k * HH + col], acc);
  support[tid] = acc;
}

// ------- kernel 2: partial[s] = adj[:, ks] @ support[ks, :] ---------------
// 256 thr: cg=tid&7 -> 4 cols; rg=tid>>3 -> rows rg, rg+32, rg+64.
// B staged in LDS (double-buffered KC-row chunks via global_load_lds w=16);
// A prefetched depth-2 in registers (explicit — compiler won't pipeline it).
__global__ __launch_bounds__(256, 4) void spmm_kernel(
    const float* __restrict__ adj,
    const float* __restrict__ support,
    float* __restrict__ partial,
    int kper) {
  __shared__ __align__(16) float ldsb[2][KC * HH];  // 2 x 20 KB

  const int rb = blockIdx.x;
  const int s = blockIdx.y;
  const int tid = threadIdx.x;
  const int cg = tid & 7;
  const int rg = tid >> 3;
  const int wave = tid >> 6;   // wave-uniform
  const int lane = tid & 63;
  const int k0 = s * kper;
  const int nchunk = kper / KC;
  const int nk4 = kper >> 2;

  const f32x4* arow0 = (const f32x4*)(adj + (size_t)(rb * BM + rg) * NN + k0);
  const f32x4* arow1 =
      (const f32x4*)(adj + (size_t)(rb * BM + rg + 32) * NN + k0);
  const f32x4* arow2 =
      (const f32x4*)(adj + (size_t)(rb * BM + rg + 64) * NN + k0);
  // staging source: wave-linear, matches gload_lds's (uniform base + lane*16)
  const char* gsrc =
      (const char*)(support + (size_t)k0 * HH) + wave * 1024 + lane * 16;

#define STAGE(buf, c)                                                        \
  {                                                                          \
    const char* gp = gsrc + (size_t)(c)*CHUNK_BYTES;                         \
    char* lp = (char*)&ldsb[buf][0] + wave * 1024;                           \
    _Pragma("unroll") for (int r = 0; r < CHUNK_BYTES / 4096; ++r)           \
        __builtin_amdgcn_global_load_lds(                                    \
            (const __attribute__((address_space(1))) unsigned int*)(gp +     \
                                                                    r * 4096), \
            (__attribute__((address_space(3))) unsigned int*)(lp + r * 4096), \
            16, 0, 0);                                                       \
  }

  // depth-2 A prefetch pipeline
  f32x4 aP0 = arow0[0], aP1 = arow1[0], aP2 = arow2[0];
  f32x4 aQ0 = arow0[1], aQ1 = arow1[1], aQ2 = arow2[1];

  STAGE(0, 0);
  __syncthreads();  // drains vmcnt(0) -> chunk 0 staged

  f32x4 acc0 = (f32x4)0.f, acc1 = (f32x4)0.f, acc2 = (f32x4)0.f;
  int kk = 0;
  int cur = 0;
  for (int c = 0; c < nchunk; ++c) {
    if (c + 1 < nchunk) STAGE(cur ^ 1, c + 1);  // issue-early (T3 2-phase)
    const float* bl = &ldsb[cur][0];
#pragma unroll 2
    for (int k4 = 0; k4 < KC / 4; ++k4) {
      const f32x4* bp = ((const f32x4*)(bl + (k4 << 7))) + cg;  // 4 rows/iter
      f32x4 b0 = bp[0];        // row 4k4+0, granule cg  (8-way broadcast,
      f32x4 b1 = bp[8];        //  8 distinct 16B addrs = conflict-free)
      f32x4 b2 = bp[16];
      f32x4 b3 = bp[24];
      int kn = kk + 2;
      kn = kn < nk4 ? kn : nk4 - 1;  // clamped tail re-read, harmless
      f32x4 aN0 = arow0[kn], aN1 = arow1[kn], aN2 = arow2[kn];
#define ROW_FMA(ACC, A)               \
      ACC += A.x * b0; ACC += A.y * b1; \
      ACC += A.z * b2; ACC += A.w * b3;
      ROW_FMA(acc0, aP0)
      ROW_FMA(acc1, aP1)
      ROW_FMA(acc2, aP2)
#undef ROW_FMA
      aP0 = aQ0; aP1 = aQ1; aP2 = aQ2;
      aQ0 = aN0; aQ1 = aN1; aQ2 = aN2;
      ++kk;
    }
    __syncthreads();  // reads of buf[cur] done; next STAGE may overwrite
    cur ^= 1;
  }
#undef STAGE

  f32x4* pout = (f32x4*)partial;
  const size_t sbase = (size_t)s * NN;
  pout[(sbase + rb * BM + rg) * (HH / 4) + cg] = acc0;
  pout[(sbase + rb * BM + rg + 32) * (HH / 4) + cg] = acc1;
  pout[(sbase + rb * BM + rg + 64) * (HH / 4) + cg] = acc2;
}

// ---------------- kernel 3: out = relu(sum_s partial + b) ----------------
__global__ void combine_kernel(const float* __restrict__ partial,
                               const float* __restrict__ bias,
                               float* __restrict__ out, int splits) {
  int tid = blockIdx.x * blockDim.x + threadIdx.x;
  if (tid >= NN * HH / 4) return;
  int c0 = (tid & (HH / 4 - 1)) * 4;
  f32x4 acc = *(const f32x4*)(bias + c0);
  for (int s = 0; s < splits; ++s)
    acc += ((const f32x4*)partial)[(size_t)s * (NN * HH / 4) + tid];
  acc.x = fmaxf(acc.x, 0.f);
  acc.y = fmaxf(acc.y, 0.f);
  acc.z = fmaxf(acc.z, 0.f);
  acc.w = fmaxf(acc.w, 0.f);
  ((f32x4*)out)[tid] = acc;
}

extern "C" void kernel_launch(void* const* d_in, const int* in_sizes, int n_in,
                              void* d_out, int out_size, void* d_ws,
                              size_t ws_size, hipStream_t stream) {
  const float* t = (const float*)d_in[0];
  const float* z = (const float*)d_in[1];
  const float* adj = (const float*)d_in[2];
  const float* treat = (const float*)d_in[3];
  const float* W = (const float*)d_in[4];
  const float* b = (const float*)d_in[5];
  float* out = (float*)d_out;

  // splits options whose kper = NN/splits is a multiple of KC=160
  const size_t elem = (size_t)NN * HH;  // floats per [N,H] buffer
  static const int split_opts[] = {15, 5, 3, 1};
  int splits = 1;
  for (int i = 0; i < 4; ++i) {
    if ((size_t)(split_opts[i] + 1) * elem * 4 <= ws_size) {
      splits = split_opts[i];
      break;
    }
  }
  const int kper = NN / splits;  // 800 / 2400 / 4000 / 12000, all % 160 == 0

  float* support = (float*)d_ws;    // NN*HH floats
  float* partial = support + elem;  // splits * NN*HH floats

  support_kernel<<<(NN * HH + 255) / 256, 256, 0, stream>>>(t, z, treat, W,
                                                            support);
  dim3 grid(NN / BM, splits);
  spmm_kernel<<<grid, 256, 0, stream>>>(adj, support, partial, kper);
  combine_kernel<<<(NN * HH / 4 + 255) / 256, 256, 0, stream>>>(partial, b, out,
                                                                splits);
}